// Round 4
// baseline (273.407 us; speedup 1.0000x reference)
//
#include <hip/hip_runtime.h>
#include <math.h>

// StateSpaceLayer: diagonal SSM scan
//   s_t = a*s_{t-1} + b*u_t ;  y_t = c*s_t + d*u_t ;  a = tanh(logit_a)
// x: (B=8, T=4096, D=1024) fp32, coefs: (D,) fp32, y: (B,T,D) fp32.
//
// R4: single-pass decoupled-lookback scan (replaces 3-kernel chunked scan).
// Accounting from R1/R3: ~156us of the timed window is poison fills (2x 512MiB
// @78us, top-5 every round); kernels+gaps were only ~105us. The controllable
// waste was pass2's full x re-read + prefix kernel + 2 launch gaps. This
// version reads x once, writes y once, and resolves inter-chunk carries
// in-kernel:
//   - ticket via atomicAdd => virtual chunk id == dispatch order => a block
//     only waits on lower tickets; lower tickets publish their aggregate
//     before any waiting of their own; chain heads publish unconditionally
//     => progress guaranteed (no dispatch-order assumption).
//   - per-WAVE flags: vmcnt is per-wave, so {4 agent-atomic state stores,
//     s_waitcnt vmcnt(0), lane0 agent-atomic flag store} needs no barrier.
//   - all cross-block state moves via agent-scope relaxed atomics (coherent
//     point; avoids buffer_wbl2/buffer_inv bulk L2 flushes of fence paths).
//   - C=64 chunks x L=64 rows: short chains (walk re-polls flag each step, so
//     depth ~= k/2); x streamed in 16-row register groups (phase A plain loads
//     to warm L2/L3, phase B nt re-read is cache-hot).
// ws: [counter u32][pad][flags 2048 u32][pad to 16KiB][agg 2MiB][pref 2MiB].
// Init kernel zeroes counter+flags each launch (ws is poisoned; replay-safe).

#define SSM_B 8
#define SSM_T 4096
#define SSM_D 1024
#define SSM_C 64                 // chunks per batch chain
#define SSM_L 64                 // rows per chunk
#define NCH   (SSM_C * SSM_B)    // 512 blocks / tickets
#define GRP   16                 // rows per register group
#define NGRP  (SSM_L / GRP)      // 4

typedef unsigned int u32;
typedef float vfloat4 __attribute__((ext_vector_type(4)));

__device__ __forceinline__ float4 f4_fma(float4 a, float4 s, float4 add) {
    return make_float4(fmaf(a.x, s.x, add.x), fmaf(a.y, s.y, add.y),
                       fmaf(a.z, s.z, add.z), fmaf(a.w, s.w, add.w));
}
__device__ __forceinline__ float4 f4_mul(float4 a, float4 b) {
    return make_float4(a.x * b.x, a.y * b.y, a.z * b.z, a.w * b.w);
}
__device__ __forceinline__ void nt_store_f4(float* p, float4 w) {
    vfloat4 v = {w.x, w.y, w.z, w.w};
    __builtin_nontemporal_store(v, (vfloat4*)p);
}
__device__ __forceinline__ float4 nt_load_f4(const float* p) {
    vfloat4 v = __builtin_nontemporal_load((const vfloat4*)p);
    return make_float4(v.x, v.y, v.z, v.w);
}
// agent-scope (device) coherent-point accessors for cross-XCD state exchange
__device__ __forceinline__ void pub_state(float* p, float4 v) {
    __hip_atomic_store(p + 0, v.x, __ATOMIC_RELAXED, __HIP_MEMORY_SCOPE_AGENT);
    __hip_atomic_store(p + 1, v.y, __ATOMIC_RELAXED, __HIP_MEMORY_SCOPE_AGENT);
    __hip_atomic_store(p + 2, v.z, __ATOMIC_RELAXED, __HIP_MEMORY_SCOPE_AGENT);
    __hip_atomic_store(p + 3, v.w, __ATOMIC_RELAXED, __HIP_MEMORY_SCOPE_AGENT);
}
__device__ __forceinline__ float4 rd_state(const float* p) {
    float4 v;
    v.x = __hip_atomic_load(p + 0, __ATOMIC_RELAXED, __HIP_MEMORY_SCOPE_AGENT);
    v.y = __hip_atomic_load(p + 1, __ATOMIC_RELAXED, __HIP_MEMORY_SCOPE_AGENT);
    v.z = __hip_atomic_load(p + 2, __ATOMIC_RELAXED, __HIP_MEMORY_SCOPE_AGENT);
    v.w = __hip_atomic_load(p + 3, __ATOMIC_RELAXED, __HIP_MEMORY_SCOPE_AGENT);
    return v;
}

__global__ __launch_bounds__(256) void ssm_init(u32* __restrict__ p) {
    // zero counter + flags region (first 4096 u32 = 16 KiB of ws)
    p[blockIdx.x * 256 + threadIdx.x] = 0u;
}

__global__ __launch_bounds__(256, 2) void ssm_scan(
        const float* __restrict__ x, const float* __restrict__ logit_a,
        const float* __restrict__ bco, const float* __restrict__ cco,
        const float* __restrict__ dco, u32* __restrict__ counter,
        u32* __restrict__ flags, float* __restrict__ agg,
        float* __restrict__ pref, float* __restrict__ y) {
    __shared__ u32 s_tix;
    if (threadIdx.x == 0) s_tix = atomicAdd(counter, 1u);
    __syncthreads();
    const u32 vk = s_tix;                 // virtual chunk id, dispatch-ordered
    const int bb = (int)(vk >> 6);        // vk / SSM_C
    const int k  = (int)(vk & (SSM_C - 1));
    const int d4 = threadIdx.x * 4;
    const int wv = threadIdx.x >> 6;      // wave id 0..3 (owns 256 channels)

    const float4 la = *(const float4*)(logit_a + d4);
    const float4 bv = *(const float4*)(bco + d4);
    const float4 cv = *(const float4*)(cco + d4);
    const float4 dv = *(const float4*)(dco + d4);
    const float4 a  = make_float4(tanhf(la.x), tanhf(la.y), tanhf(la.z), tanhf(la.w));
    float4 aL = a;
#pragma unroll
    for (int i = 0; i < 6; ++i) aL = f4_mul(aL, aL);   // a^64 = a^L

    const size_t cbase = ((size_t)bb * SSM_T + (size_t)k * SSM_L) * SSM_D + d4;
    const float* xp = x + cbase;

    // ---- phase A: local end-state over L=64 rows, 16-row register groups
    //      (plain loads: warm L2/L3 for the phase-B re-read)
    float4 e = make_float4(0.f, 0.f, 0.f, 0.f);
#pragma unroll
    for (int g = 0; g < NGRP; ++g) {
        float4 u[GRP];
#pragma unroll
        for (int t = 0; t < GRP; ++t)
            u[t] = *(const float4*)(xp + (size_t)(g * GRP + t) * SSM_D);
#pragma unroll
        for (int t = 0; t < GRP; ++t) e = f4_fma(a, e, f4_mul(bv, u[t]));
    }

    // ---- publish aggregate (chain heads go straight to prefix)
    u32* myflag = flags + (vk << 2) + wv;
    if (k > 0) {
        pub_state(agg + ((size_t)vk << 10) + d4, e);
        asm volatile("s_waitcnt vmcnt(0)" ::: "memory");   // wave's stores done
        if ((threadIdx.x & 63) == 0)
            __hip_atomic_store(myflag, 1u, __ATOMIC_RELAXED,
                               __HIP_MEMORY_SCOPE_AGENT);
    }

    // ---- lookback: state at chunk start = sum_{j<k} aL^(k-1-j) * E_j
    //      walk back over aggregates, stop at first full prefix (flag==2)
    float4 s = make_float4(0.f, 0.f, 0.f, 0.f);
    if (k > 0) {
        float4 m = make_float4(1.f, 1.f, 1.f, 1.f);
        int j = (int)vk - 1;
        for (;;) {
            u32 f;
            int tries = 1 << 20;                 // emergency bail (never hit)
            do {
                f = __hip_atomic_load(flags + (j << 2) + wv, __ATOMIC_RELAXED,
                                      __HIP_MEMORY_SCOPE_AGENT);
                f = (u32)__builtin_amdgcn_readfirstlane((int)f);
            } while (f == 0u && --tries > 0);
            if (f == 0u) break;
            const float* sp =
                (f >= 2u ? pref : agg) + ((size_t)j << 10) + d4;
            float4 v = rd_state(sp);
            s = f4_fma(m, v, s);
            if (f >= 2u) break;                  // folded a full prefix: done
            m = f4_mul(m, aL);
            --j;                                 // head has flag==2, loop ends
        }
    }

    // ---- publish inclusive prefix P = aL*s_start + E (skip chain tail)
    if (k != SSM_C - 1) {
        float4 P = f4_fma(aL, s, e);
        pub_state(pref + ((size_t)vk << 10) + d4, P);
        asm volatile("s_waitcnt vmcnt(0)" ::: "memory");
        if ((threadIdx.x & 63) == 0)
            __hip_atomic_store(myflag, 2u, __ATOMIC_RELAXED,
                               __HIP_MEMORY_SCOPE_AGENT);
    }

    // ---- phase B: exact recurrence from s, write y (x re-read is cache-hot)
    float* yp = y + cbase;
#pragma unroll
    for (int g = 0; g < NGRP; ++g) {
        float4 u[GRP];
#pragma unroll
        for (int t = 0; t < GRP; ++t)
            u[t] = nt_load_f4(xp + (size_t)(g * GRP + t) * SSM_D);
#pragma unroll
        for (int t = 0; t < GRP; ++t) {
            s = f4_fma(a, s, f4_mul(bv, u[t]));
            u[t] = f4_fma(cv, s, f4_mul(dv, u[t]));
        }
#pragma unroll
        for (int t = 0; t < GRP; ++t)
            nt_store_f4(yp + (size_t)(g * GRP + t) * SSM_D, u[t]);
    }
}

extern "C" void kernel_launch(void* const* d_in, const int* in_sizes, int n_in,
                              void* d_out, int out_size, void* d_ws, size_t ws_size,
                              hipStream_t stream) {
    const float* x   = (const float*)d_in[0];
    const float* la  = (const float*)d_in[1];
    const float* bco = (const float*)d_in[2];
    const float* cco = (const float*)d_in[3];
    const float* dco = (const float*)d_in[4];
    float* y = (float*)d_out;

    u32*   counter = (u32*)d_ws;                    // [0]       : ticket
    u32*   flags   = (u32*)d_ws + 64;               // [256B]    : 2048 flags
    float* agg     = (float*)d_ws + 4096;           // [16KiB]   : 2 MiB
    float* pref    = agg + (size_t)NCH * SSM_D;     // [+2MiB]   : 2 MiB

    ssm_init<<<dim3(16), dim3(256), 0, stream>>>((u32*)d_ws);  // 16 KiB zero
    ssm_scan<<<dim3(NCH), dim3(256), 0, stream>>>(x, la, bco, cco, dco,
                                                  counter, flags, agg, pref, y);
}

// Round 8
// 259.560 us; speedup vs baseline: 1.0533x; 1.0533x over previous
//
#include <hip/hip_runtime.h>
#include <math.h>

// StateSpaceLayer: diagonal SSM scan
//   s_t = a*s_{t-1} + b*u_t ;  y_t = c*s_t + d*u_t ;  a = tanh(logit_a)
// x: (B=8, T=4096, D=1024) fp32, coefs: (D,) fp32, y: (B,T,D) fp32.
//
// R8: ZERO-SYNC fallback after 3 consecutive "container failed twice" rounds
// (R5/R6/R7, incl. a near-verbatim copy of R4 which ran fine) — structure
// identical to the R0/R2/R3 kernels that benched successfully; if this also
// fails, infra is conclusively broken.
//   Structure = R3's 3-kernel chunked scan + validated levers:
//   - C=32 / L=128 (long chunks; prefix kernel shrinks to 32 serial steps,
//     ws traffic 16 MiB -> 2 MiB)
//   - 16-row register groups in both passes (R3's verified win: 16
//     independent dwordx4 loads issued back-to-back, THEN the dependent FMA
//     chain; pass2 ends each group with 16 nt stores)
//   - prefix batches all 32 chunk-end loads into regs before its serial scan
//   pass1 : per-chunk local end state (zero init)      -> ws.chunk_end (1 MiB)
//   prefix: serial per-channel scan over chunk ends    -> ws.chunk_start (1 MiB)
//   pass2 : load own start state, exact recurrence, write y.
// No inter-block communication anywhere: deadlock-impossible by construction.

#define SSM_B 8
#define SSM_T 4096
#define SSM_D 1024
#define SSM_C 32                 // chunks
#define SSM_L 128                // chunk length = T / C
#define GRP   16                 // rows per register group
#define NGRP  (SSM_L / GRP)      // 8 sequential groups

typedef float vfloat4 __attribute__((ext_vector_type(4)));

__device__ __forceinline__ float4 f4_fma(float4 a, float4 s, float4 add) {
    return make_float4(fmaf(a.x, s.x, add.x), fmaf(a.y, s.y, add.y),
                       fmaf(a.z, s.z, add.z), fmaf(a.w, s.w, add.w));
}
__device__ __forceinline__ float4 f4_mul(float4 a, float4 b) {
    return make_float4(a.x * b.x, a.y * b.y, a.z * b.z, a.w * b.w);
}
__device__ __forceinline__ void nt_store_f4(float* p, float4 w) {
    vfloat4 v = {w.x, w.y, w.z, w.w};
    __builtin_nontemporal_store(v, (vfloat4*)p);
}
__device__ __forceinline__ float4 nt_load_f4(const float* p) {
    vfloat4 v = __builtin_nontemporal_load((const vfloat4*)p);
    return make_float4(v.x, v.y, v.z, v.w);
}

__global__ __launch_bounds__(256, 1) void ssm_pass1(
        const float* __restrict__ x, const float* __restrict__ logit_a,
        const float* __restrict__ bco, float* __restrict__ chunk_end) {
    const int k  = blockIdx.x;          // chunk index
    const int bb = blockIdx.y;          // batch index
    const int d4 = threadIdx.x * 4;     // 256 threads cover D=1024

    float4 la = *(const float4*)(logit_a + d4);
    float4 bv = *(const float4*)(bco + d4);
    float4 a  = make_float4(tanhf(la.x), tanhf(la.y), tanhf(la.z), tanhf(la.w));

    const float* xp = x + ((size_t)bb * SSM_T + (size_t)k * SSM_L) * SSM_D + d4;

    float4 e = make_float4(0.f, 0.f, 0.f, 0.f);
#pragma unroll
    for (int g = 0; g < NGRP; ++g) {
        float4 u[GRP];                  // load phase: 16 independent 16B loads
#pragma unroll
        for (int t = 0; t < GRP; ++t)
            u[t] = *(const float4*)(xp + (size_t)(g * GRP + t) * SSM_D);
#pragma unroll
        for (int t = 0; t < GRP; ++t) e = f4_fma(a, e, f4_mul(bv, u[t]));
    }
    *(float4*)(chunk_end + ((size_t)k * SSM_B + bb) * SSM_D + d4) = e;
}

// One scalar thread per (batch, channel): exclusive scan over chunk end-states.
//   chunk_start[k] = sum_{j<k} a^(L*(k-1-j)) * chunk_end[j]
// All 32 chunk_end loads batched into regs (static indexing) before the scan.
__global__ __launch_bounds__(256) void ssm_prefix(
        const float* __restrict__ logit_a,
        const float* __restrict__ chunk_end,
        float* __restrict__ chunk_start) {
    const int tid = blockIdx.x * 256 + threadIdx.x;  // [0, B*D)
    const int d   = tid & (SSM_D - 1);

    float a  = tanhf(logit_a[d]);
    float aL = a;
#pragma unroll
    for (int i = 0; i < 7; ++i) aL *= aL;            // a^L, L = 128

    const size_t stride = (size_t)SSM_B * SSM_D;
    float ce[SSM_C];
#pragma unroll
    for (int j = 0; j < SSM_C; ++j)                  // 32 independent loads
        ce[j] = chunk_end[(size_t)tid + (size_t)j * stride];

    float s = 0.f;
#pragma unroll
    for (int j = 0; j < SSM_C; ++j) {
        chunk_start[(size_t)tid + (size_t)j * stride] = s;
        s = fmaf(aL, s, ce[j]);
    }
}

__global__ __launch_bounds__(256, 1) void ssm_pass2(
        const float* __restrict__ x, const float* __restrict__ logit_a,
        const float* __restrict__ bco, const float* __restrict__ cco,
        const float* __restrict__ dco, const float* __restrict__ chunk_start,
        float* __restrict__ y) {
    const int k  = blockIdx.x;
    const int bb = blockIdx.y;
    const int d4 = threadIdx.x * 4;

    float4 la = *(const float4*)(logit_a + d4);
    float4 bv = *(const float4*)(bco + d4);
    float4 cv = *(const float4*)(cco + d4);
    float4 dv = *(const float4*)(dco + d4);
    float4 a  = make_float4(tanhf(la.x), tanhf(la.y), tanhf(la.z), tanhf(la.w));

    // initial state for this chunk: one coalesced 16B load per thread
    float4 s = *(const float4*)(chunk_start + ((size_t)k * SSM_B + bb) * SSM_D + d4);

    const size_t base = ((size_t)bb * SSM_T + (size_t)k * SSM_L) * SSM_D + d4;
    const float* xp = x + base;
    float*       yp = y + base;

#pragma unroll
    for (int g = 0; g < NGRP; ++g) {
        float4 u[GRP];                  // load phase: 16 independent nt loads
#pragma unroll
        for (int t = 0; t < GRP; ++t)
            u[t] = nt_load_f4(xp + (size_t)(g * GRP + t) * SSM_D);
#pragma unroll
        for (int t = 0; t < GRP; ++t) { // compute: overwrite u[t] with y_t
            s = f4_fma(a, s, f4_mul(bv, u[t]));
            u[t] = f4_fma(cv, s, f4_mul(dv, u[t]));
        }
#pragma unroll
        for (int t = 0; t < GRP; ++t)   // store phase: 16 independent nt stores
            nt_store_f4(yp + (size_t)(g * GRP + t) * SSM_D, u[t]);
    }
}

extern "C" void kernel_launch(void* const* d_in, const int* in_sizes, int n_in,
                              void* d_out, int out_size, void* d_ws, size_t ws_size,
                              hipStream_t stream) {
    const float* x   = (const float*)d_in[0];
    const float* la  = (const float*)d_in[1];
    const float* bco = (const float*)d_in[2];
    const float* cco = (const float*)d_in[3];
    const float* dco = (const float*)d_in[4];
    float* y = (float*)d_out;
    float* chunk_end   = (float*)d_ws;                                  // 1 MiB
    float* chunk_start = (float*)d_ws + (size_t)SSM_C * SSM_B * SSM_D;  // 1 MiB

    dim3 grid(SSM_C, SSM_B);            // 256 blocks -> 1 block/CU
    dim3 block(256);
    ssm_pass1<<<grid, block, 0, stream>>>(x, la, bco, chunk_end);
    ssm_prefix<<<dim3((SSM_B * SSM_D) / 256), block, 0, stream>>>(la, chunk_end, chunk_start);
    ssm_pass2<<<grid, block, 0, stream>>>(x, la, bco, cco, dco, chunk_start, y);
}